// Round 4
// baseline (234.747 us; speedup 1.0000x reference)
//
#include <hip/hip_runtime.h>
#include <math.h>

// Problem constants (from reference setup_inputs)
constexpr int B = 16;
constexpr int S = 4096;
constexpr int F = 512;
constexpr int L = 32;        // output s-positions per thread
constexpr int HALO = 16;     // prefix window reach: k=31 -> p=15, need P[t-16]
constexpr int NV = L + 2 * HALO;  // 64 staged float2 values per thread
constexpr int BLOCK = 256;   // threads per block; each thread owns TWO f (float2)
constexpr int F2 = F / 2;    // row stride in float2 units (256)

// clang native vector type: __builtin_nontemporal_store accepts this
// (HIP's float2 is a struct and is rejected -- round-3 compile failure).
typedef float f32x2 __attribute__((ext_vector_type(2)));

// out[b,t,f] = sum_i softmax(w)[i]/k_i * sum_{d=-p_i}^{p_i} x[b, clamp(t+d), f]
//
// Structure (proven rounds 0->2): load-all-then-compute burst, in-register
// prefix sum, outputs as prefix differences, NT stores.
// Round-3/4 change: float2 per thread along F. Halves VMEM instruction count,
// doubles bytes-in-flight per wave (64 x dwordx2 = 32 KB), one block covers
// all 512 features. Data state 64 f32x2 = 128 VGPRs (+overhead ~155) -- under
// the spill cliff that bit round 1 (tripwire: WRITE_SIZE must stay ~131 MB).
__global__ __launch_bounds__(BLOCK) void msavg_kernel(
    const float* __restrict__ x, const float* __restrict__ kw,
    float* __restrict__ out) {
  const int f2 = threadIdx.x;          // float2 lane: covers f = 2*f2, 2*f2+1
  const int t0 = blockIdx.x * L;       // chunk start along S
  const int b  = blockIdx.y;

  // softmax over the 4 scale weights, folded with 1/k (uniform -> scalar regs)
  float w0 = kw[0], w1 = kw[1], w2 = kw[2], w3 = kw[3];
  float m  = fmaxf(fmaxf(w0, w1), fmaxf(w2, w3));
  float e0 = expf(w0 - m), e1 = expf(w1 - m), e2 = expf(w2 - m), e3 = expf(w3 - m);
  float inv = 1.0f / (e0 + e1 + e2 + e3);
  const float c3  = e0 * inv * (1.0f / 3.0f);
  const float c7  = e1 * inv * (1.0f / 7.0f);
  const float c15 = e2 * inv * (1.0f / 15.0f);
  const float c31 = e3 * inv * (1.0f / 31.0f);

  const f32x2* xb = (const f32x2*)(x   + ((size_t)b * S) * F) + f2;
  f32x2*       ob = (f32x2*)      (out + ((size_t)b * S) * F) + f2;

  // ---- Phase 1: one burst of NV independent dwordx2 loads ----
  f32x2 v[NV];
  if (t0 - HALO >= 0 && t0 + L - 1 + HALO <= S - 1) {
    // interior fast path: no clamping
    const f32x2* p0 = xb + (size_t)(t0 - HALO) * F2;
#pragma unroll
    for (int j = 0; j < NV; ++j) v[j] = p0[(size_t)j * F2];
  } else {
    // edge chunks (blockIdx.x == 0 or == S/L-1): clamp == replicate padding
#pragma unroll
    for (int j = 0; j < NV; ++j) {
      int s = t0 - HALO + j;
      s = s < 0 ? 0 : (s > S - 1 ? S - 1 : s);
      v[j] = xb[(size_t)s * F2];
    }
  }
  // Pin the full load burst above the serial prefix chain (round-0 lesson:
  // otherwise the compiler register-minimizes into load/wait/add bursts and
  // the kernel goes latency-bound at ~2.5 TB/s).
  __builtin_amdgcn_sched_barrier(0);

  // ---- Phase 2: in-place component-wise prefix sum ----
  {
    f32x2 p = {0.0f, 0.0f};
#pragma unroll
    for (int j = 0; j < NV; ++j) {
      p += v[j];
      v[j] = p;
    }
  }

  // ---- Phase 3: 32 outputs, t = t0 + i. P[s] == v[s - (t0-16)] ----
  // window sum k: P[t + p_k] - P[t - p_k - 1]
#pragma unroll
  for (int i = 0; i < L; ++i) {
    f32x2 o = c3  * (v[i + 17] - v[i + 14]) +
              c7  * (v[i + 19] - v[i + 12]) +
              c15 * (v[i + 23] - v[i + 8 ]) +
              c31 * (v[i + 31] - v[i     ]);
    // non-temporal: output never re-read; don't evict input halo from L2/LLC
    __builtin_nontemporal_store(o, &ob[(size_t)(t0 + i) * F2]);
  }
}

extern "C" void kernel_launch(void* const* d_in, const int* in_sizes, int n_in,
                              void* d_out, int out_size, void* d_ws, size_t ws_size,
                              hipStream_t stream) {
  const float* x  = (const float*)d_in[0];  // [16, 4096, 512] fp32
  const float* kw = (const float*)d_in[1];  // [4] fp32
  float* out = (float*)d_out;               // [16, 4096, 512] fp32
  (void)in_sizes; (void)n_in; (void)out_size; (void)d_ws; (void)ws_size;

  dim3 grid(S / L, B);  // (128, 16) = 2048 blocks, 4 waves each
  msavg_kernel<<<grid, BLOCK, 0, stream>>>(x, kw, out);
}